// Round 1
// baseline (10279.222 us; speedup 1.0000x reference)
//
#include <hip/hip_runtime.h>
#include <hip/hip_bf16.h>
#include <math.h>

// LSTM decoder: B=64, T=512, IN=256, OUT=256, H=1024, 2 layers + linear head.
// Round 5: latency-focused redesign of the per-step exchange.
//  - Flag-vector grid barrier: block bid arrives via one relaxed 4B agent
//    store to flags[bid]; wave 0 polls all 256 flags with 2x8B agent loads
//    per lane (no same-line atomic RMW chains, no 2-level counters).
//  - h publications coalesced: cells write LDS staging; wave 0 publishes
//    64 x 8B agent stores per buffer. h1[t-1] is published in step t's
//    window so there is ONE vmcnt drain point per step.
//  - Projection spread over 64 blocks (16 cols x 16 batch each) and run in
//    the arrive->wait window. h1 has 4 slots (slot 3 for the tail publish).
//  - Kept: cached h reads + one agent-acquire (buffer_inv) per step
//    (measured FETCH shows the L2 absorbs the broadcast), phase structure.

typedef __attribute__((ext_vector_type(8))) short bf16x8;   // 8 x bf16
typedef __attribute__((ext_vector_type(4))) float f32x4;
typedef unsigned long long u64;

__device__ __forceinline__ float sigm(float v) { return 1.f / (1.f + expf(-v)); }

__device__ __forceinline__ unsigned short bf16_bits(float v) {
  __hip_bfloat16 hb = __float2bfloat16(v);
  unsigned short us;
  __builtin_memcpy(&us, &hb, 2);
  return us;
}

// write-through (sc0 sc1) 2B store (prep only)
__device__ __forceinline__ void vstore_bf16(__hip_bfloat16* p, float v) {
  *(volatile unsigned short*)p = bf16_bits(v);
}

// ---------------- prep kernels (one-time per launch) ----------------

// W0cat[u*4+g][k] : k<256 -> Wih0[g*1024+u][k], else Whh0[g*1024+u][k-256]
__global__ __launch_bounds__(256) void prep_w0(const float* __restrict__ Wih0,
                                               const float* __restrict__ Whh0,
                                               __hip_bfloat16* __restrict__ W0) {
  const unsigned n = 4096u * 1280u;
  for (unsigned d = blockIdx.x * blockDim.x + threadIdx.x; d < n;
       d += blockDim.x * gridDim.x) {
    unsigned r = d / 1280u;
    unsigned k = d - r * 1280u;
    unsigned u = r >> 2, g = r & 3u;
    unsigned srow = g * 1024u + u;
    float v = (k < 256u) ? Wih0[(size_t)srow * 256u + k]
                         : Whh0[(size_t)srow * 1024u + (k - 256u)];
    W0[d] = __float2bfloat16(v);
  }
}

// W1ext[4352][2048]: rows<4096 reordered LSTM1 weights [Wih1|Whh1];
// rows 4096+o: [zeros(1024) | Wlin[o]]
__global__ __launch_bounds__(256) void prep_w1(const float* __restrict__ Wih1,
                                               const float* __restrict__ Whh1,
                                               const float* __restrict__ Wlin,
                                               __hip_bfloat16* __restrict__ W1) {
  const unsigned n = 4352u * 2048u;
  for (unsigned d = blockIdx.x * blockDim.x + threadIdx.x; d < n;
       d += blockDim.x * gridDim.x) {
    unsigned r = d >> 11;
    unsigned k = d & 2047u;
    float v;
    if (r < 4096u) {
      unsigned u = r >> 2, g = r & 3u;
      unsigned srow = g * 1024u + u;
      v = (k < 1024u) ? Wih1[(size_t)srow * 1024u + k]
                      : Whh1[(size_t)srow * 1024u + (k - 1024u)];
    } else {
      unsigned o = r - 4096u;
      v = (k < 1024u) ? 0.f : Wlin[(size_t)o * 1024u + (k - 1024u)];
    }
    W1[d] = __float2bfloat16(v);
  }
}

// xbf[t][b][k] = bf16( t==0 ? 0 : x[b][t-1][k] )   (teacher forcing shift)
__global__ __launch_bounds__(256) void prep_x(const float* __restrict__ x,
                                              __hip_bfloat16* __restrict__ xbf) {
  const unsigned n = 512u * 64u * 256u;
  for (unsigned d = blockIdx.x * blockDim.x + threadIdx.x; d < n;
       d += blockDim.x * gridDim.x) {
    unsigned t = d >> 14;
    unsigned b = (d >> 8) & 63u;
    unsigned k = d & 255u;
    float v = (t == 0u) ? 0.f : x[((size_t)b * 512u + (t - 1u)) * 256u + k];
    xbf[d] = __float2bfloat16(v);
  }
}

// biases (gate-interleaved, bih+bhh combined) + h init: h0[-1] -> slot 0,
// h1[-1] -> slot 2 (h1[tau] lives in slot tau%3; tau=-1 -> 2)
__global__ __launch_bounds__(256) void prep_misc(
    const float* __restrict__ bih0, const float* __restrict__ bhh0,
    const float* __restrict__ bih1, const float* __restrict__ bhh1,
    const float* __restrict__ z, float* __restrict__ b0, float* __restrict__ b1,
    __hip_bfloat16* __restrict__ h0buf, __hip_bfloat16* __restrict__ h1buf) {
  for (int i = blockIdx.x * blockDim.x + threadIdx.x; i < 73728;
       i += blockDim.x * gridDim.x) {
    if (i < 4096) {
      int u = i >> 2, g = i & 3;
      b0[i] = bih0[g * 1024 + u] + bhh0[g * 1024 + u];
    } else if (i < 8192) {
      int r = i - 4096;
      int u = r >> 2, g = r & 3;
      b1[r] = bih1[g * 1024 + u] + bhh1[g * 1024 + u];
    } else {
      int j = i - 8192;  // 0..65535
      float zv = z[j];
      vstore_bf16(h0buf + j, zv);                       // h0 slot 0
      vstore_bf16(h1buf + 2 * 65536 + j, zv);           // h1 slot 2
    }
  }
}

// ---------------- projection helper (blocks 0..63) ----------------
// out[pbat*16 .. +16, t_out, pcol*16 .. +16) = h1p @ Wlin^T + blin
// Each block: 16 out-cols x 16 batch rows; K=1024 split over 8 waves.

__device__ __forceinline__ void do_proj(const __hip_bfloat16* __restrict__ h1p,
                                        const bf16x8* wp, float (*red)[16][68],
                                        const float* __restrict__ blin,
                                        float* __restrict__ out, int pcol,
                                        int pbat, int t_out, int tid, int w,
                                        int col, int kq) {
  f32x4 a0 = {0.f, 0.f, 0.f, 0.f};
  const __hip_bfloat16* ab =
      h1p + ((size_t)((pbat << 4) + col) << 10) + (w << 7) + (kq << 3);
#pragma unroll
  for (int c = 0; c < 4; ++c) {
    bf16x8 f = *(const bf16x8*)(ab + (c << 5));
    a0 = __builtin_amdgcn_mfma_f32_16x16x32_bf16(f, wp[c], a0, 0, 0, 0);
  }
  *(f32x4*)&red[w][col][(kq << 2)] = a0;
  __syncthreads();
  if (tid < 256) {
    int o_l = tid & 15, b = tid >> 4;  // b: 0..15
    float v = blin[(pcol << 4) + o_l];
#pragma unroll
    for (int ww = 0; ww < 8; ++ww) v += red[ww][o_l][b];
    out[(((size_t)((pbat << 4) + b) << 9) + (size_t)t_out) * 256 + (pcol << 4) +
        o_l] = v;
  }
  // no trailing sync: every call site is followed by a block-wide barrier
  // before red is written again.
}

// ---------------- persistent kernel ----------------

__global__ __launch_bounds__(512) void k_persist(
    const __hip_bfloat16* __restrict__ xbf, const __hip_bfloat16* __restrict__ W0,
    const __hip_bfloat16* __restrict__ W1, const float* __restrict__ b0,
    const float* __restrict__ b1, const float* __restrict__ blin,
    __hip_bfloat16* __restrict__ h0buf, __hip_bfloat16* __restrict__ h1buf,
    float* __restrict__ out, unsigned* __restrict__ flags) {
  const int tid = threadIdx.x;
  const int lane = tid & 63;
  const int w = tid >> 6;          // wave id = K-split index (0..7)
  const int bid = blockIdx.x;
  const int cb = bid << 4;         // 16 gate-columns owned by this block
  const int col = lane & 15;
  const int kq = lane >> 4;
  const int n = cb + col;
  const bool isproj = (bid < 64);
  const int pcol = bid & 15;       // proj: out-col tile
  const int pbat = (bid >> 4) & 3; // proj: batch tile

  // ---- weights -> registers (persist across all 512 steps) ----
  bf16x8 wa[5], wb[8], wp[4];
  {
    const __hip_bfloat16* p = W0 + (size_t)n * 1280 + w * 160 + (kq << 3);
#pragma unroll
    for (int c = 0; c < 5; ++c) wa[c] = *(const bf16x8*)(p + (c << 5));
  }
  {
    const __hip_bfloat16* p = W1 + ((size_t)n << 11) + (w << 8) + (kq << 3);
#pragma unroll
    for (int c = 0; c < 8; ++c) wb[c] = *(const bf16x8*)(p + (c << 5));
  }
  if (isproj) {
    const __hip_bfloat16* p = W1 +
        ((size_t)(4096 + (pcol << 4) + col) << 11) + 1024 + (w << 7) + (kq << 3);
#pragma unroll
    for (int c = 0; c < 4; ++c) wp[c] = *(const bf16x8*)(p + (c << 5));
  }

  // cell threads: tid<256 own (unit u_l of 4, batch bq); c-state in registers
  const int u_l = tid & 3, bq = tid >> 2;
  float bias0[4], bias1[4];
  if (tid < 256) {
#pragma unroll
    for (int g = 0; g < 4; ++g) {
      bias0[g] = b0[cb + (u_l << 2) + g];
      bias1[g] = b1[cb + (u_l << 2) + g];
    }
  }
  float c0v = 0.f, c1v = 0.f;

  __shared__ float red[8][16][68];        // K-partials; 68 keeps 16B alignment
  __shared__ unsigned short hst0[64][4];  // h0[t] staging (row-major)
  __shared__ unsigned short hst1[64][4];  // h1[t] staging

  for (int t = 0; t < 512; ++t) {
    const __hip_bfloat16* h0prev = h0buf + ((size_t)(t & 1) << 16);
    const __hip_bfloat16* h0cur = h0buf + ((size_t)((t + 1) & 1) << 16);
    const __hip_bfloat16* h1prev = h1buf + ((size_t)((t + 2) % 3) << 16);

    // ======== phase A: gates0 = [x_t | h0prev] @ W0cat^T ========
    {
      f32x4 a0 = {0.f, 0.f, 0.f, 0.f}, a1 = a0, a2 = a0, a3 = a0;
#pragma unroll
      for (int c = 0; c < 5; ++c) {
        const int k0 = w * 160 + (c << 5);
        const __hip_bfloat16* ab;
        size_t rs;
        if (k0 < 256) {  // x part (L2-cached)
          ab = xbf + ((size_t)t << 14) + k0 + (kq << 3);
          rs = 256;
        } else {         // h part (L2-hot: B_{t-1} pulled it fresh post-inv)
          ab = h0prev + (k0 - 256) + (kq << 3);
          rs = 1024;
        }
        bf16x8 f0 = *(const bf16x8*)(ab + (size_t)col * rs);
        bf16x8 f1 = *(const bf16x8*)(ab + (size_t)(16 + col) * rs);
        bf16x8 f2 = *(const bf16x8*)(ab + (size_t)(32 + col) * rs);
        bf16x8 f3 = *(const bf16x8*)(ab + (size_t)(48 + col) * rs);
        a0 = __builtin_amdgcn_mfma_f32_16x16x32_bf16(f0, wa[c], a0, 0, 0, 0);
        a1 = __builtin_amdgcn_mfma_f32_16x16x32_bf16(f1, wa[c], a1, 0, 0, 0);
        a2 = __builtin_amdgcn_mfma_f32_16x16x32_bf16(f2, wa[c], a2, 0, 0, 0);
        a3 = __builtin_amdgcn_mfma_f32_16x16x32_bf16(f3, wa[c], a3, 0, 0, 0);
      }
      *(f32x4*)&red[w][col][(kq << 2)] = a0;
      *(f32x4*)&red[w][col][16 + (kq << 2)] = a1;
      *(f32x4*)&red[w][col][32 + (kq << 2)] = a2;
      *(f32x4*)&red[w][col][48 + (kq << 2)] = a3;
    }
    __syncthreads();
    if (tid < 256) {  // 8-way K-reduce + LSTM cell 0 -> LDS staging
      float gg[4];
#pragma unroll
      for (int g = 0; g < 4; ++g) {
        float v = bias0[g];
#pragma unroll
        for (int ww = 0; ww < 8; ++ww) v += red[ww][(u_l << 2) + g][bq];
        gg[g] = v;
      }
      float cn = sigm(gg[1]) * c0v + sigm(gg[0]) * tanhf(gg[2]);
      c0v = cn;
      hst0[bq][u_l] = bf16_bits(sigm(gg[3]) * tanhf(cn));
    }
    __syncthreads();

    // ---- arrive: publish h0[t] (+ h1[t-1]) coalesced, then flag ----
    if (w == 0) {
      u64 v0;
      __builtin_memcpy(&v0, &hst0[lane][0], 8);
      __hip_atomic_store((u64*)(h0buf + (((size_t)((t + 1) & 1)) << 16) +
                                ((size_t)lane << 10) + (cb >> 2)),
                         v0, __ATOMIC_RELAXED, __HIP_MEMORY_SCOPE_AGENT);
      if (t > 0) {  // h1[t-1] -> slot (t-1)%3 == (t+2)%3
        u64 v1;
        __builtin_memcpy(&v1, &hst1[lane][0], 8);
        __hip_atomic_store((u64*)(h1buf + (((size_t)((t + 2) % 3)) << 16) +
                                  ((size_t)lane << 10) + (cb >> 2)),
                           v1, __ATOMIC_RELAXED, __HIP_MEMORY_SCOPE_AGENT);
      }
      __builtin_amdgcn_s_waitcnt(0);          // drain publishes to LLC
      __builtin_amdgcn_sched_barrier(0);      // keep flag after the drain
      if (lane == 0)
        __hip_atomic_store(&flags[bid], (unsigned)(t + 1), __ATOMIC_RELAXED,
                           __HIP_MEMORY_SCOPE_AGENT);
    }

    // proj out[t-2] from h1[t-2] (slot (t-2)%3 == (t+1)%3) in the window.
    // Operand is L2-fresh: B_{t-1} read it after the last buffer_inv.
    if (isproj && t >= 2)
      do_proj(h1buf + (((size_t)((t + 1) % 3)) << 16), wp, red, blin, out,
              pcol, pbat, t - 2, tid, w, col, kq);

    // ---- wait: poll all 256 flags, then agent-acquire (buffer_inv) ----
    if (w == 0) {
      const unsigned tgt = (unsigned)(t + 1);
      const u64* fq = (const u64*)flags;
      for (;;) {
        u64 q0 = __hip_atomic_load(&fq[2 * lane], __ATOMIC_RELAXED,
                                   __HIP_MEMORY_SCOPE_AGENT);
        u64 q1 = __hip_atomic_load(&fq[2 * lane + 1], __ATOMIC_RELAXED,
                                   __HIP_MEMORY_SCOPE_AGENT);
        int ok = ((unsigned)q0 >= tgt) & ((unsigned)(q0 >> 32) >= tgt) &
                 ((unsigned)q1 >= tgt) & ((unsigned)(q1 >> 32) >= tgt);
        if (__all(ok)) break;
        __builtin_amdgcn_s_sleep(1);
      }
      // acquire: s_waitcnt + buffer_inv (L1+L2, no writeback); per-CU/XCD
      // physical op -> one wave suffices for the whole block.
      __builtin_amdgcn_fence(__ATOMIC_ACQUIRE, "agent");
    }
    __syncthreads();

    // ======== phase B: gates1 = [h0cur | h1prev] @ W1^T ========
    {
      const __hip_bfloat16* ab =
          ((w < 4) ? h0cur : h1prev) + ((w & 3) << 8) + (kq << 3);
      f32x4 a0 = {0.f, 0.f, 0.f, 0.f}, a1 = a0, a2 = a0, a3 = a0;
#pragma unroll
      for (int c = 0; c < 8; ++c) {
        const __hip_bfloat16* p = ab + (c << 5);
        bf16x8 f0 = *(const bf16x8*)(p + ((size_t)col << 10));
        bf16x8 f1 = *(const bf16x8*)(p + ((size_t)(16 + col) << 10));
        bf16x8 f2 = *(const bf16x8*)(p + ((size_t)(32 + col) << 10));
        bf16x8 f3 = *(const bf16x8*)(p + ((size_t)(48 + col) << 10));
        a0 = __builtin_amdgcn_mfma_f32_16x16x32_bf16(f0, wb[c], a0, 0, 0, 0);
        a1 = __builtin_amdgcn_mfma_f32_16x16x32_bf16(f1, wb[c], a1, 0, 0, 0);
        a2 = __builtin_amdgcn_mfma_f32_16x16x32_bf16(f2, wb[c], a2, 0, 0, 0);
        a3 = __builtin_amdgcn_mfma_f32_16x16x32_bf16(f3, wb[c], a3, 0, 0, 0);
      }
      *(f32x4*)&red[w][col][(kq << 2)] = a0;
      *(f32x4*)&red[w][col][16 + (kq << 2)] = a1;
      *(f32x4*)&red[w][col][32 + (kq << 2)] = a2;
      *(f32x4*)&red[w][col][48 + (kq << 2)] = a3;
    }
    __syncthreads();
    if (tid < 256) {  // 8-way K-reduce + LSTM cell 1 -> LDS staging
      float gg[4];
#pragma unroll
      for (int g = 0; g < 4; ++g) {
        float v = bias1[g];
#pragma unroll
        for (int ww = 0; ww < 8; ++ww) v += red[ww][(u_l << 2) + g][bq];
        gg[g] = v;
      }
      float cn = sigm(gg[1]) * c1v + sigm(gg[0]) * tanhf(gg[2]);
      c1v = cn;
      hst1[bq][u_l] = bf16_bits(sigm(gg[3]) * tanhf(cn));
    }
    __syncthreads();  // red + hst1 safe before next iteration
  }

  // ---- tail: out[510] from h1[510] (slot 0, L2-fresh via B_511) ----
  if (isproj)
    do_proj(h1buf, wp, red, blin, out, pcol, pbat, 510, tid, w, col, kq);

  // publish h1[511] to spare slot 3 and run one final flag phase
  if (w == 0) {
    u64 v1;
    __builtin_memcpy(&v1, &hst1[lane][0], 8);
    __hip_atomic_store((u64*)(h1buf + ((size_t)3 << 16) +
                              ((size_t)lane << 10) + (cb >> 2)),
                       v1, __ATOMIC_RELAXED, __HIP_MEMORY_SCOPE_AGENT);
    __builtin_amdgcn_s_waitcnt(0);
    __builtin_amdgcn_sched_barrier(0);
    if (lane == 0)
      __hip_atomic_store(&flags[bid], 513u, __ATOMIC_RELAXED,
                         __HIP_MEMORY_SCOPE_AGENT);
  }
  if (!isproj) return;
  if (w == 0) {
    const u64* fq = (const u64*)flags;
    for (;;) {
      u64 q0 = __hip_atomic_load(&fq[2 * lane], __ATOMIC_RELAXED,
                                 __HIP_MEMORY_SCOPE_AGENT);
      u64 q1 = __hip_atomic_load(&fq[2 * lane + 1], __ATOMIC_RELAXED,
                                 __HIP_MEMORY_SCOPE_AGENT);
      int ok = ((unsigned)q0 >= 513u) & ((unsigned)(q0 >> 32) >= 513u) &
               ((unsigned)q1 >= 513u) & ((unsigned)(q1 >> 32) >= 513u);
      if (__all(ok)) break;
      __builtin_amdgcn_s_sleep(1);
    }
    __builtin_amdgcn_fence(__ATOMIC_ACQUIRE, "agent");
  }
  __syncthreads();
  do_proj(h1buf + ((size_t)3 << 16), wp, red, blin, out, pcol, pbat, 511, tid,
          w, col, kq);
}

// ---------------- host launch ----------------

extern "C" void kernel_launch(void* const* d_in, const int* in_sizes, int n_in,
                              void* d_out, int out_size, void* d_ws, size_t ws_size,
                              hipStream_t stream) {
  const float* z = (const float*)d_in[0];
  const float* x = (const float*)d_in[1];
  const float* Wih0 = (const float*)d_in[2];
  const float* Whh0 = (const float*)d_in[3];
  const float* bih0 = (const float*)d_in[4];
  const float* bhh0 = (const float*)d_in[5];
  const float* Wih1 = (const float*)d_in[6];
  const float* Whh1 = (const float*)d_in[7];
  const float* bih1 = (const float*)d_in[8];
  const float* bhh1 = (const float*)d_in[9];
  const float* Wlin = (const float*)d_in[10];
  const float* blin = (const float*)d_in[11];
  float* out = (float*)d_out;

  char* ws = (char*)d_ws;
  __hip_bfloat16* W0 = (__hip_bfloat16*)(ws);                // 10,485,760 B
  __hip_bfloat16* W1 = (__hip_bfloat16*)(ws + 10485760);     // 17,825,792 B
  __hip_bfloat16* xbf = (__hip_bfloat16*)(ws + 28311552);    // 16,777,216 B
  float* b0 = (float*)(ws + 45088768);                       // 16,384 B
  float* b1 = (float*)(ws + 45105152);                       // 16,384 B
  __hip_bfloat16* h0buf = (__hip_bfloat16*)(ws + 45121536);  // 262,144 B (2 slots)
  __hip_bfloat16* h1buf = (__hip_bfloat16*)(ws + 45383680);  // 524,288 B (4 slots)
  unsigned* flags = (unsigned*)(ws + 45907968);              // 4,096 B

  hipMemsetAsync(flags, 0, 4096, stream);  // ws is re-poisoned every call
  prep_w0<<<4096, 256, 0, stream>>>(Wih0, Whh0, W0);
  prep_w1<<<4096, 256, 0, stream>>>(Wih1, Whh1, Wlin, W1);
  prep_x<<<4096, 256, 0, stream>>>(x, xbf);
  prep_misc<<<288, 256, 0, stream>>>(bih0, bhh0, bih1, bhh1, z, b0, b1, h0buf,
                                     h1buf);

  k_persist<<<256, 512, 0, stream>>>(xbf, W0, W1, b0, b1, blin, h0buf, h1buf,
                                     out, flags);
}

// Round 2
// 9461.488 us; speedup vs baseline: 1.0864x; 1.0864x over previous
//
#include <hip/hip_runtime.h>
#include <hip/hip_bf16.h>
#include <math.h>

// LSTM decoder: B=64, T=512, IN=256, OUT=256, H=1024, 2 layers + linear head.
// Round 6: attack the per-step agent-acquire (buffer_inv = full L1+L2
// invalidate) that BOTH prior rounds executed per block per step in the
// critical wait path (32 L2-invalidates per XCD per step; suspected
// serialized at the L2 controller ~= the unexplained ~13us/step).
//  - Leader election per XCD via s_getreg(HW_REG_XCC_ID) + atomic claim
//    (plus bid<8 as redundant cover). Only leaders issue the agent fence
//    (L1+L2 inv); all other blocks issue plain buffer_inv (L1-only).
//  - Fence relocated OUT of the wait path into the shadow (post-A,
//    pre-publish). Correct by slot rotation: every stale-fill->rewrite->
//    reread pair for h0 (2 slots) / h1 (3 slots) spans >=1 per-step fence,
//    and leader fence(t) is globally after all blocks' step t-1 fills
//    (leader passed poll(t-1) which required every block's flag).
//  - Wait path is now: poll flags -> __syncthreads -> phase B (no fence).
//  - Everything else (flag barrier, coalesced publish, proj in window)
//    kept from R5.

typedef __attribute__((ext_vector_type(8))) short bf16x8;   // 8 x bf16
typedef __attribute__((ext_vector_type(4))) float f32x4;
typedef unsigned long long u64;

__device__ __forceinline__ float sigm(float v) { return 1.f / (1.f + expf(-v)); }

__device__ __forceinline__ unsigned short bf16_bits(float v) {
  __hip_bfloat16 hb = __float2bfloat16(v);
  unsigned short us;
  __builtin_memcpy(&us, &hb, 2);
  return us;
}

// write-through (sc0 sc1) 2B store (prep only)
__device__ __forceinline__ void vstore_bf16(__hip_bfloat16* p, float v) {
  *(volatile unsigned short*)p = bf16_bits(v);
}

// ---------------- prep kernels (one-time per launch) ----------------

// W0cat[u*4+g][k] : k<256 -> Wih0[g*1024+u][k], else Whh0[g*1024+u][k-256]
__global__ __launch_bounds__(256) void prep_w0(const float* __restrict__ Wih0,
                                               const float* __restrict__ Whh0,
                                               __hip_bfloat16* __restrict__ W0) {
  const unsigned n = 4096u * 1280u;
  for (unsigned d = blockIdx.x * blockDim.x + threadIdx.x; d < n;
       d += blockDim.x * gridDim.x) {
    unsigned r = d / 1280u;
    unsigned k = d - r * 1280u;
    unsigned u = r >> 2, g = r & 3u;
    unsigned srow = g * 1024u + u;
    float v = (k < 256u) ? Wih0[(size_t)srow * 256u + k]
                         : Whh0[(size_t)srow * 1024u + (k - 256u)];
    W0[d] = __float2bfloat16(v);
  }
}

// W1ext[4352][2048]: rows<4096 reordered LSTM1 weights [Wih1|Whh1];
// rows 4096+o: [zeros(1024) | Wlin[o]]
__global__ __launch_bounds__(256) void prep_w1(const float* __restrict__ Wih1,
                                               const float* __restrict__ Whh1,
                                               const float* __restrict__ Wlin,
                                               __hip_bfloat16* __restrict__ W1) {
  const unsigned n = 4352u * 2048u;
  for (unsigned d = blockIdx.x * blockDim.x + threadIdx.x; d < n;
       d += blockDim.x * gridDim.x) {
    unsigned r = d >> 11;
    unsigned k = d & 2047u;
    float v;
    if (r < 4096u) {
      unsigned u = r >> 2, g = r & 3u;
      unsigned srow = g * 1024u + u;
      v = (k < 1024u) ? Wih1[(size_t)srow * 1024u + k]
                      : Whh1[(size_t)srow * 1024u + (k - 1024u)];
    } else {
      unsigned o = r - 4096u;
      v = (k < 1024u) ? 0.f : Wlin[(size_t)o * 1024u + (k - 1024u)];
    }
    W1[d] = __float2bfloat16(v);
  }
}

// xbf[t][b][k] = bf16( t==0 ? 0 : x[b][t-1][k] )   (teacher forcing shift)
__global__ __launch_bounds__(256) void prep_x(const float* __restrict__ x,
                                              __hip_bfloat16* __restrict__ xbf) {
  const unsigned n = 512u * 64u * 256u;
  for (unsigned d = blockIdx.x * blockDim.x + threadIdx.x; d < n;
       d += blockDim.x * gridDim.x) {
    unsigned t = d >> 14;
    unsigned b = (d >> 8) & 63u;
    unsigned k = d & 255u;
    float v = (t == 0u) ? 0.f : x[((size_t)b * 512u + (t - 1u)) * 256u + k];
    xbf[d] = __float2bfloat16(v);
  }
}

// biases (gate-interleaved, bih+bhh combined) + h init: h0[-1] -> slot 0,
// h1[-1] -> slot 2 (h1[tau] lives in slot tau%3; tau=-1 -> 2)
__global__ __launch_bounds__(256) void prep_misc(
    const float* __restrict__ bih0, const float* __restrict__ bhh0,
    const float* __restrict__ bih1, const float* __restrict__ bhh1,
    const float* __restrict__ z, float* __restrict__ b0, float* __restrict__ b1,
    __hip_bfloat16* __restrict__ h0buf, __hip_bfloat16* __restrict__ h1buf) {
  for (int i = blockIdx.x * blockDim.x + threadIdx.x; i < 73728;
       i += blockDim.x * gridDim.x) {
    if (i < 4096) {
      int u = i >> 2, g = i & 3;
      b0[i] = bih0[g * 1024 + u] + bhh0[g * 1024 + u];
    } else if (i < 8192) {
      int r = i - 4096;
      int u = r >> 2, g = r & 3;
      b1[r] = bih1[g * 1024 + u] + bhh1[g * 1024 + u];
    } else {
      int j = i - 8192;  // 0..65535
      float zv = z[j];
      vstore_bf16(h0buf + j, zv);                       // h0 slot 0
      vstore_bf16(h1buf + 2 * 65536 + j, zv);           // h1 slot 2
    }
  }
}

// ---------------- projection helper (blocks 0..63) ----------------
// out[pbat*16 .. +16, t_out, pcol*16 .. +16) = h1p @ Wlin^T + blin
// Each block: 16 out-cols x 16 batch rows; K=1024 split over 8 waves.

__device__ __forceinline__ void do_proj(const __hip_bfloat16* __restrict__ h1p,
                                        const bf16x8* wp, float (*red)[16][68],
                                        const float* __restrict__ blin,
                                        float* __restrict__ out, int pcol,
                                        int pbat, int t_out, int tid, int w,
                                        int col, int kq) {
  f32x4 a0 = {0.f, 0.f, 0.f, 0.f};
  const __hip_bfloat16* ab =
      h1p + ((size_t)((pbat << 4) + col) << 10) + (w << 7) + (kq << 3);
#pragma unroll
  for (int c = 0; c < 4; ++c) {
    bf16x8 f = *(const bf16x8*)(ab + (c << 5));
    a0 = __builtin_amdgcn_mfma_f32_16x16x32_bf16(f, wp[c], a0, 0, 0, 0);
  }
  *(f32x4*)&red[w][col][(kq << 2)] = a0;
  __syncthreads();
  if (tid < 256) {
    int o_l = tid & 15, b = tid >> 4;  // b: 0..15
    float v = blin[(pcol << 4) + o_l];
#pragma unroll
    for (int ww = 0; ww < 8; ++ww) v += red[ww][o_l][b];
    out[(((size_t)((pbat << 4) + b) << 9) + (size_t)t_out) * 256 + (pcol << 4) +
        o_l] = v;
  }
  // no trailing sync: every call site is followed by a block-wide barrier
  // before red is written again.
}

// ---------------- persistent kernel ----------------

__global__ __launch_bounds__(512) void k_persist(
    const __hip_bfloat16* __restrict__ xbf, const __hip_bfloat16* __restrict__ W0,
    const __hip_bfloat16* __restrict__ W1, const float* __restrict__ b0,
    const float* __restrict__ b1, const float* __restrict__ blin,
    __hip_bfloat16* __restrict__ h0buf, __hip_bfloat16* __restrict__ h1buf,
    float* __restrict__ out, unsigned* __restrict__ flags) {
  const int tid = threadIdx.x;
  const int lane = tid & 63;
  const int w = tid >> 6;          // wave id = K-split index (0..7)
  const int bid = blockIdx.x;
  const int cb = bid << 4;         // 16 gate-columns owned by this block
  const int col = lane & 15;
  const int kq = lane >> 4;
  const int n = cb + col;
  const bool isproj = (bid < 64);
  const int pcol = bid & 15;       // proj: out-col tile
  const int pbat = (bid >> 4) & 3; // proj: batch tile

  // ---- per-XCD leader election (one heavy L2-inv per XCD per step) ----
  __shared__ int s_lead;
  {
    unsigned* lead = flags + 256;  // 8 claim slots (zeroed by host memset)
    if (tid == 0) {
      unsigned xcc = 0;
      asm volatile("s_getreg_b32 %0, hwreg(HW_REG_XCC_ID)" : "=s"(xcc));
      unsigned old = __hip_atomic_fetch_add(&lead[xcc & 7u], 1u,
                                            __ATOMIC_RELAXED,
                                            __HIP_MEMORY_SCOPE_AGENT);
      // elected leader of this XCD, plus bid<8 as redundant cover
      s_lead = (old == 0u || bid < 8) ? 1 : 0;
    }
  }

  // ---- weights -> registers (persist across all 512 steps) ----
  bf16x8 wa[5], wb[8], wp[4];
  {
    const __hip_bfloat16* p = W0 + (size_t)n * 1280 + w * 160 + (kq << 3);
#pragma unroll
    for (int c = 0; c < 5; ++c) wa[c] = *(const bf16x8*)(p + (c << 5));
  }
  {
    const __hip_bfloat16* p = W1 + ((size_t)n << 11) + (w << 8) + (kq << 3);
#pragma unroll
    for (int c = 0; c < 8; ++c) wb[c] = *(const bf16x8*)(p + (c << 5));
  }
  if (isproj) {
    const __hip_bfloat16* p = W1 +
        ((size_t)(4096 + (pcol << 4) + col) << 11) + 1024 + (w << 7) + (kq << 3);
#pragma unroll
    for (int c = 0; c < 4; ++c) wp[c] = *(const bf16x8*)(p + (c << 5));
  }

  // cell threads: tid<256 own (unit u_l of 4, batch bq); c-state in registers
  const int u_l = tid & 3, bq = tid >> 2;
  float bias0[4], bias1[4];
  if (tid < 256) {
#pragma unroll
    for (int g = 0; g < 4; ++g) {
      bias0[g] = b0[cb + (u_l << 2) + g];
      bias1[g] = b1[cb + (u_l << 2) + g];
    }
  }
  float c0v = 0.f, c1v = 0.f;

  __shared__ float red[8][16][68];        // K-partials; 68 keeps 16B alignment
  __shared__ unsigned short hst0[64][4];  // h0[t] staging (row-major)
  __shared__ unsigned short hst1[64][4];  // h1[t] staging

  __syncthreads();  // s_lead visible to all waves

  for (int t = 0; t < 512; ++t) {
    const __hip_bfloat16* h0prev = h0buf + ((size_t)(t & 1) << 16);
    const __hip_bfloat16* h0cur = h0buf + ((size_t)((t + 1) & 1) << 16);
    const __hip_bfloat16* h1prev = h1buf + ((size_t)((t + 2) % 3) << 16);

    // ======== phase A: gates0 = [x_t | h0prev] @ W0cat^T ========
    // h0prev lines are L1/L2-warm from phase B(t-1) (fence comes AFTER A).
    {
      f32x4 a0 = {0.f, 0.f, 0.f, 0.f}, a1 = a0, a2 = a0, a3 = a0;
#pragma unroll
      for (int c = 0; c < 5; ++c) {
        const int k0 = w * 160 + (c << 5);
        const __hip_bfloat16* ab;
        size_t rs;
        if (k0 < 256) {  // x part
          ab = xbf + ((size_t)t << 14) + k0 + (kq << 3);
          rs = 256;
        } else {         // h part
          ab = h0prev + (k0 - 256) + (kq << 3);
          rs = 1024;
        }
        bf16x8 f0 = *(const bf16x8*)(ab + (size_t)col * rs);
        bf16x8 f1 = *(const bf16x8*)(ab + (size_t)(16 + col) * rs);
        bf16x8 f2 = *(const bf16x8*)(ab + (size_t)(32 + col) * rs);
        bf16x8 f3 = *(const bf16x8*)(ab + (size_t)(48 + col) * rs);
        a0 = __builtin_amdgcn_mfma_f32_16x16x32_bf16(f0, wa[c], a0, 0, 0, 0);
        a1 = __builtin_amdgcn_mfma_f32_16x16x32_bf16(f1, wa[c], a1, 0, 0, 0);
        a2 = __builtin_amdgcn_mfma_f32_16x16x32_bf16(f2, wa[c], a2, 0, 0, 0);
        a3 = __builtin_amdgcn_mfma_f32_16x16x32_bf16(f3, wa[c], a3, 0, 0, 0);
      }
      *(f32x4*)&red[w][col][(kq << 2)] = a0;
      *(f32x4*)&red[w][col][16 + (kq << 2)] = a1;
      *(f32x4*)&red[w][col][32 + (kq << 2)] = a2;
      *(f32x4*)&red[w][col][48 + (kq << 2)] = a3;
    }
    __syncthreads();
    if (tid < 256) {  // 8-way K-reduce + LSTM cell 0 -> LDS staging
      float gg[4];
#pragma unroll
      for (int g = 0; g < 4; ++g) {
        float v = bias0[g];
#pragma unroll
        for (int ww = 0; ww < 8; ++ww) v += red[ww][(u_l << 2) + g][bq];
        gg[g] = v;
      }
      float cn = sigm(gg[1]) * c0v + sigm(gg[0]) * tanhf(gg[2]);
      c0v = cn;
      hst0[bq][u_l] = bf16_bits(sigm(gg[3]) * tanhf(cn));
    }
    __syncthreads();

    // ---- shadow fence + publish + flag (w0 only) ----
    if (w == 0) {
      // cache hygiene OUT of the wait path: leader invalidates L1+L2 for
      // the whole XCD; others invalidate only their own CU's L1.
      __builtin_amdgcn_s_waitcnt(0);
      if (s_lead) {
        __builtin_amdgcn_fence(__ATOMIC_ACQUIRE, "agent");  // waitcnt+buffer_inv(L1+L2)
      } else {
        __builtin_amdgcn_sched_barrier(0);
        asm volatile("buffer_inv" ::: "memory");            // L1-only inv
        __builtin_amdgcn_sched_barrier(0);
      }
      u64 v0;
      __builtin_memcpy(&v0, &hst0[lane][0], 8);
      __hip_atomic_store((u64*)(h0buf + (((size_t)((t + 1) & 1)) << 16) +
                                ((size_t)lane << 10) + (cb >> 2)),
                         v0, __ATOMIC_RELAXED, __HIP_MEMORY_SCOPE_AGENT);
      if (t > 0) {  // h1[t-1] -> slot (t-1)%3 == (t+2)%3
        u64 v1;
        __builtin_memcpy(&v1, &hst1[lane][0], 8);
        __hip_atomic_store((u64*)(h1buf + (((size_t)((t + 2) % 3)) << 16) +
                                  ((size_t)lane << 10) + (cb >> 2)),
                           v1, __ATOMIC_RELAXED, __HIP_MEMORY_SCOPE_AGENT);
      }
      __builtin_amdgcn_s_waitcnt(0);          // drain publishes to LLC
      __builtin_amdgcn_sched_barrier(0);      // keep flag after the drain
      if (lane == 0)
        __hip_atomic_store(&flags[bid], (unsigned)(t + 1), __ATOMIC_RELAXED,
                           __HIP_MEMORY_SCOPE_AGENT);
    }

    // proj out[t-2] from h1[t-2] (slot (t-2)%3 == (t+1)%3) in the window.
    // Runs after this block's fence, so L1/L2 refill is LLC-fresh.
    if (isproj && t >= 2)
      do_proj(h1buf + (((size_t)((t + 1) % 3)) << 16), wp, red, blin, out,
              pcol, pbat, t - 2, tid, w, col, kq);

    // ---- wait: poll all 256 flags; NO fence in the wait path ----
    if (w == 0) {
      const unsigned tgt = (unsigned)(t + 1);
      const u64* fq = (const u64*)flags;
      for (;;) {
        u64 q0 = __hip_atomic_load(&fq[2 * lane], __ATOMIC_RELAXED,
                                   __HIP_MEMORY_SCOPE_AGENT);
        u64 q1 = __hip_atomic_load(&fq[2 * lane + 1], __ATOMIC_RELAXED,
                                   __HIP_MEMORY_SCOPE_AGENT);
        int ok = ((unsigned)q0 >= tgt) & ((unsigned)(q0 >> 32) >= tgt) &
                 ((unsigned)q1 >= tgt) & ((unsigned)(q1 >> 32) >= tgt);
        if (__all(ok)) break;
        __builtin_amdgcn_s_sleep(1);
      }
    }
    __syncthreads();

    // ======== phase B: gates1 = [h0cur | h1prev] @ W1^T ========
    // Slot lines were dropped by this XCD's leader-inv before any flag of
    // step t was raised; L2 misses refill from the (complete) LLC copy.
    {
      const __hip_bfloat16* ab =
          ((w < 4) ? h0cur : h1prev) + ((w & 3) << 8) + (kq << 3);
      f32x4 a0 = {0.f, 0.f, 0.f, 0.f}, a1 = a0, a2 = a0, a3 = a0;
#pragma unroll
      for (int c = 0; c < 8; ++c) {
        const __hip_bfloat16* p = ab + (c << 5);
        bf16x8 f0 = *(const bf16x8*)(p + ((size_t)col << 10));
        bf16x8 f1 = *(const bf16x8*)(p + ((size_t)(16 + col) << 10));
        bf16x8 f2 = *(const bf16x8*)(p + ((size_t)(32 + col) << 10));
        bf16x8 f3 = *(const bf16x8*)(p + ((size_t)(48 + col) << 10));
        a0 = __builtin_amdgcn_mfma_f32_16x16x32_bf16(f0, wb[c], a0, 0, 0, 0);
        a1 = __builtin_amdgcn_mfma_f32_16x16x32_bf16(f1, wb[c], a1, 0, 0, 0);
        a2 = __builtin_amdgcn_mfma_f32_16x16x32_bf16(f2, wb[c], a2, 0, 0, 0);
        a3 = __builtin_amdgcn_mfma_f32_16x16x32_bf16(f3, wb[c], a3, 0, 0, 0);
      }
      *(f32x4*)&red[w][col][(kq << 2)] = a0;
      *(f32x4*)&red[w][col][16 + (kq << 2)] = a1;
      *(f32x4*)&red[w][col][32 + (kq << 2)] = a2;
      *(f32x4*)&red[w][col][48 + (kq << 2)] = a3;
    }
    __syncthreads();
    if (tid < 256) {  // 8-way K-reduce + LSTM cell 1 -> LDS staging
      float gg[4];
#pragma unroll
      for (int g = 0; g < 4; ++g) {
        float v = bias1[g];
#pragma unroll
        for (int ww = 0; ww < 8; ++ww) v += red[ww][(u_l << 2) + g][bq];
        gg[g] = v;
      }
      float cn = sigm(gg[1]) * c1v + sigm(gg[0]) * tanhf(gg[2]);
      c1v = cn;
      hst1[bq][u_l] = bf16_bits(sigm(gg[3]) * tanhf(cn));
    }
    __syncthreads();  // red + hst1 safe before next iteration
  }

  // ---- tail: out[510] from h1[510] (slot 0, fresh via B_511's read) ----
  if (isproj)
    do_proj(h1buf, wp, red, blin, out, pcol, pbat, 510, tid, w, col, kq);

  // publish h1[511] to spare slot 3 and run one final flag phase
  if (w == 0) {
    u64 v1;
    __builtin_memcpy(&v1, &hst1[lane][0], 8);
    __hip_atomic_store((u64*)(h1buf + ((size_t)3 << 16) +
                              ((size_t)lane << 10) + (cb >> 2)),
                       v1, __ATOMIC_RELAXED, __HIP_MEMORY_SCOPE_AGENT);
    __builtin_amdgcn_s_waitcnt(0);
    __builtin_amdgcn_sched_barrier(0);
    if (lane == 0)
      __hip_atomic_store(&flags[bid], 513u, __ATOMIC_RELAXED,
                         __HIP_MEMORY_SCOPE_AGENT);
  }
  if (!isproj) return;
  if (w == 0) {
    const u64* fq = (const u64*)flags;
    for (;;) {
      u64 q0 = __hip_atomic_load(&fq[2 * lane], __ATOMIC_RELAXED,
                                 __HIP_MEMORY_SCOPE_AGENT);
      u64 q1 = __hip_atomic_load(&fq[2 * lane + 1], __ATOMIC_RELAXED,
                                 __HIP_MEMORY_SCOPE_AGENT);
      int ok = ((unsigned)q0 >= 513u) & ((unsigned)(q0 >> 32) >= 513u) &
               ((unsigned)q1 >= 513u) & ((unsigned)(q1 >> 32) >= 513u);
      if (__all(ok)) break;
      __builtin_amdgcn_s_sleep(1);
    }
    // conservative: full agent acquire once (slot 3 never cached before,
    // but the fence is one-time and removes any doubt)
    __builtin_amdgcn_fence(__ATOMIC_ACQUIRE, "agent");
  }
  __syncthreads();
  do_proj(h1buf + ((size_t)3 << 16), wp, red, blin, out, pcol, pbat, 511, tid,
          w, col, kq);
}

// ---------------- host launch ----------------

extern "C" void kernel_launch(void* const* d_in, const int* in_sizes, int n_in,
                              void* d_out, int out_size, void* d_ws, size_t ws_size,
                              hipStream_t stream) {
  const float* z = (const float*)d_in[0];
  const float* x = (const float*)d_in[1];
  const float* Wih0 = (const float*)d_in[2];
  const float* Whh0 = (const float*)d_in[3];
  const float* bih0 = (const float*)d_in[4];
  const float* bhh0 = (const float*)d_in[5];
  const float* Wih1 = (const float*)d_in[6];
  const float* Whh1 = (const float*)d_in[7];
  const float* bih1 = (const float*)d_in[8];
  const float* bhh1 = (const float*)d_in[9];
  const float* Wlin = (const float*)d_in[10];
  const float* blin = (const float*)d_in[11];
  float* out = (float*)d_out;

  char* ws = (char*)d_ws;
  __hip_bfloat16* W0 = (__hip_bfloat16*)(ws);                // 10,485,760 B
  __hip_bfloat16* W1 = (__hip_bfloat16*)(ws + 10485760);     // 17,825,792 B
  __hip_bfloat16* xbf = (__hip_bfloat16*)(ws + 28311552);    // 16,777,216 B
  float* b0 = (float*)(ws + 45088768);                       // 16,384 B
  float* b1 = (float*)(ws + 45105152);                       // 16,384 B
  __hip_bfloat16* h0buf = (__hip_bfloat16*)(ws + 45121536);  // 262,144 B (2 slots)
  __hip_bfloat16* h1buf = (__hip_bfloat16*)(ws + 45383680);  // 524,288 B (4 slots)
  unsigned* flags = (unsigned*)(ws + 45907968);              // 4,096 B (flags+lead)

  hipMemsetAsync(flags, 0, 4096, stream);  // ws is re-poisoned every call
  prep_w0<<<4096, 256, 0, stream>>>(Wih0, Whh0, W0);
  prep_w1<<<4096, 256, 0, stream>>>(Wih1, Whh1, Wlin, W1);
  prep_x<<<4096, 256, 0, stream>>>(x, xbf);
  prep_misc<<<288, 256, 0, stream>>>(bih0, bhh0, bih1, bhh1, z, b0, b1, h0buf,
                                     h1buf);

  k_persist<<<256, 512, 0, stream>>>(xbf, W0, W1, b0, b1, blin, h0buf, h1buf,
                                     out, flags);
}

// Round 4
// 9436.118 us; speedup vs baseline: 1.0893x; 1.0027x over previous
//
#include <hip/hip_runtime.h>
#include <hip/hip_bf16.h>
#include <math.h>

// LSTM decoder: B=64, T=512, IN=256, OUT=256, H=1024, 2 layers + linear head.
// Round 8 = Round 7 resubmitted after container failure, with the single
// unproven construct (`asm "buffer_inv sc1"`) replaced by the proven
// agent-acquire fence builtin (compiles+runs per R5/R6). Design:
//  - Cell threads publish h directly (2B sc1 stores) at cell end: publish
//    issue starts earlier, spread across 4 waves, no LDS staging pass.
//  - Leader blocks (1 elected per XCD + bid>=248 belt): full agent acquire
//    (waitcnt + L1/L2 inv) in the shadow window. Non-leaders: plain
//    `buffer_inv` (L1-only, drain-free — proven asm from R6).
//  - Window order: inv -> proj (blocks 64..127) / x[t+1] prefetch (others,
//    post-inv so lines survive into A(t+1)) -> per-wave waitcnt(0) (publish
//    drain, now overlapped) -> flag -> poll. Drain rides under real work.
//  - Fast cell math (__expf-based sigmoid/tanh).
//  - Barrier between tail's two do_proj calls (red reuse race fix).

typedef __attribute__((ext_vector_type(8))) short bf16x8;   // 8 x bf16
typedef __attribute__((ext_vector_type(4))) float f32x4;
typedef unsigned long long u64;

__device__ __forceinline__ float sigm(float v) {
  return 1.f / (1.f + __expf(-v));
}
__device__ __forceinline__ float ftanh(float v) {
  return 2.f / (1.f + __expf(-2.f * v)) - 1.f;
}

__device__ __forceinline__ unsigned short bf16_bits(float v) {
  __hip_bfloat16 hb = __float2bfloat16(v);
  unsigned short us;
  __builtin_memcpy(&us, &hb, 2);
  return us;
}

// write-through (sc0 sc1) 2B store
__device__ __forceinline__ void vstore_bf16(__hip_bfloat16* p, float v) {
  *(volatile unsigned short*)p = bf16_bits(v);
}

// ---------------- prep kernels (one-time per launch) ----------------

// W0cat[u*4+g][k] : k<256 -> Wih0[g*1024+u][k], else Whh0[g*1024+u][k-256]
__global__ __launch_bounds__(256) void prep_w0(const float* __restrict__ Wih0,
                                               const float* __restrict__ Whh0,
                                               __hip_bfloat16* __restrict__ W0) {
  const unsigned n = 4096u * 1280u;
  for (unsigned d = blockIdx.x * blockDim.x + threadIdx.x; d < n;
       d += blockDim.x * gridDim.x) {
    unsigned r = d / 1280u;
    unsigned k = d - r * 1280u;
    unsigned u = r >> 2, g = r & 3u;
    unsigned srow = g * 1024u + u;
    float v = (k < 256u) ? Wih0[(size_t)srow * 256u + k]
                         : Whh0[(size_t)srow * 1024u + (k - 256u)];
    W0[d] = __float2bfloat16(v);
  }
}

// W1ext[4352][2048]: rows<4096 reordered LSTM1 weights [Wih1|Whh1];
// rows 4096+o: [zeros(1024) | Wlin[o]]
__global__ __launch_bounds__(256) void prep_w1(const float* __restrict__ Wih1,
                                               const float* __restrict__ Whh1,
                                               const float* __restrict__ Wlin,
                                               __hip_bfloat16* __restrict__ W1) {
  const unsigned n = 4352u * 2048u;
  for (unsigned d = blockIdx.x * blockDim.x + threadIdx.x; d < n;
       d += blockDim.x * gridDim.x) {
    unsigned r = d >> 11;
    unsigned k = d & 2047u;
    float v;
    if (r < 4096u) {
      unsigned u = r >> 2, g = r & 3u;
      unsigned srow = g * 1024u + u;
      v = (k < 1024u) ? Wih1[(size_t)srow * 1024u + k]
                      : Whh1[(size_t)srow * 1024u + (k - 1024u)];
    } else {
      unsigned o = r - 4096u;
      v = (k < 1024u) ? 0.f : Wlin[(size_t)o * 1024u + (k - 1024u)];
    }
    W1[d] = __float2bfloat16(v);
  }
}

// xbf[t][b][k] = bf16( t==0 ? 0 : x[b][t-1][k] )   (teacher forcing shift)
__global__ __launch_bounds__(256) void prep_x(const float* __restrict__ x,
                                              __hip_bfloat16* __restrict__ xbf) {
  const unsigned n = 512u * 64u * 256u;
  for (unsigned d = blockIdx.x * blockDim.x + threadIdx.x; d < n;
       d += blockDim.x * gridDim.x) {
    unsigned t = d >> 14;
    unsigned b = (d >> 8) & 63u;
    unsigned k = d & 255u;
    float v = (t == 0u) ? 0.f : x[((size_t)b * 512u + (t - 1u)) * 256u + k];
    xbf[d] = __float2bfloat16(v);
  }
}

// biases (gate-interleaved, bih+bhh combined) + h init: h0[-1] -> slot 0,
// h1[-1] -> slot 2 (h1[tau] lives in slot tau%3; tau=-1 -> 2)
__global__ __launch_bounds__(256) void prep_misc(
    const float* __restrict__ bih0, const float* __restrict__ bhh0,
    const float* __restrict__ bih1, const float* __restrict__ bhh1,
    const float* __restrict__ z, float* __restrict__ b0, float* __restrict__ b1,
    __hip_bfloat16* __restrict__ h0buf, __hip_bfloat16* __restrict__ h1buf) {
  for (int i = blockIdx.x * blockDim.x + threadIdx.x; i < 73728;
       i += blockDim.x * gridDim.x) {
    if (i < 4096) {
      int u = i >> 2, g = i & 3;
      b0[i] = bih0[g * 1024 + u] + bhh0[g * 1024 + u];
    } else if (i < 8192) {
      int r = i - 4096;
      int u = r >> 2, g = r & 3;
      b1[r] = bih1[g * 1024 + u] + bhh1[g * 1024 + u];
    } else {
      int j = i - 8192;  // 0..65535
      float zv = z[j];
      vstore_bf16(h0buf + j, zv);                       // h0 slot 0
      vstore_bf16(h1buf + 2 * 65536 + j, zv);           // h1 slot 2
    }
  }
}

// ---------------- projection helper (blocks 64..127) ----------------
// out[pbat*16 .. +16, t_out, pcol*16 .. +16) = h1p @ Wlin^T + blin

__device__ __forceinline__ void do_proj(const __hip_bfloat16* __restrict__ h1p,
                                        const bf16x8* wp, float (*red)[16][68],
                                        const float* __restrict__ blin,
                                        float* __restrict__ out, int pcol,
                                        int pbat, int t_out, int tid, int w,
                                        int col, int kq) {
  f32x4 a0 = {0.f, 0.f, 0.f, 0.f};
  const __hip_bfloat16* ab =
      h1p + ((size_t)((pbat << 4) + col) << 10) + (w << 7) + (kq << 3);
#pragma unroll
  for (int c = 0; c < 4; ++c) {
    bf16x8 f = *(const bf16x8*)(ab + (c << 5));
    a0 = __builtin_amdgcn_mfma_f32_16x16x32_bf16(f, wp[c], a0, 0, 0, 0);
  }
  *(f32x4*)&red[w][col][(kq << 2)] = a0;
  __syncthreads();
  if (tid < 256) {
    int o_l = tid & 15, b = tid >> 4;  // b: 0..15
    float v = blin[(pcol << 4) + o_l];
#pragma unroll
    for (int ww = 0; ww < 8; ++ww) v += red[ww][o_l][b];
    out[(((size_t)((pbat << 4) + b) << 9) + (size_t)t_out) * 256 + (pcol << 4) +
        o_l] = v;
  }
  // no trailing sync: every call site is followed by a block-wide barrier
  // before red is written again.
}

// ---------------- persistent kernel ----------------

__global__ __launch_bounds__(512) void k_persist(
    const __hip_bfloat16* __restrict__ xbf, const __hip_bfloat16* __restrict__ W0,
    const __hip_bfloat16* __restrict__ W1, const float* __restrict__ b0,
    const float* __restrict__ b1, const float* __restrict__ blin,
    __hip_bfloat16* __restrict__ h0buf, __hip_bfloat16* __restrict__ h1buf,
    float* __restrict__ out, unsigned* __restrict__ flags) {
  const int tid = threadIdx.x;
  const int lane = tid & 63;
  const int w = tid >> 6;          // wave id = K-split index (0..7)
  const int bid = blockIdx.x;
  const int cb = bid << 4;         // 16 gate-columns owned by this block
  const int col = lane & 15;
  const int kq = lane >> 4;
  const int n = cb + col;
  const bool isproj = (bid >= 64 && bid < 128);
  const int pcol = bid & 15;       // proj: out-col tile
  const int pbat = (bid >> 4) & 3; // proj: batch tile

  // ---- per-XCD leader election (one L2-inv per XCD per step) ----
  __shared__ int s_lead;
  {
    unsigned* lead = flags + 256;  // 8 claim slots (zeroed by host memset)
    if (tid == 0) {
      unsigned xcc = 0;
      asm volatile("s_getreg_b32 %0, hwreg(HW_REG_XCC_ID)" : "=s"(xcc));
      unsigned old = __hip_atomic_fetch_add(&lead[xcc & 7u], 1u,
                                            __ATOMIC_RELAXED,
                                            __HIP_MEMORY_SCOPE_AGENT);
      // elected leader of this XCD; bid>=248 (non-proj) as redundant cover
      s_lead = (old == 0u || bid >= 248) ? 1 : 0;
    }
  }

  // ---- weights -> registers (persist across all 512 steps) ----
  bf16x8 wa[5], wb[8], wp[4];
  {
    const __hip_bfloat16* p = W0 + (size_t)n * 1280 + w * 160 + (kq << 3);
#pragma unroll
    for (int c = 0; c < 5; ++c) wa[c] = *(const bf16x8*)(p + (c << 5));
  }
  {
    const __hip_bfloat16* p = W1 + ((size_t)n << 11) + (w << 8) + (kq << 3);
#pragma unroll
    for (int c = 0; c < 8; ++c) wb[c] = *(const bf16x8*)(p + (c << 5));
  }
  if (isproj) {
    const __hip_bfloat16* p = W1 +
        ((size_t)(4096 + (pcol << 4) + col) << 11) + 1024 + (w << 7) + (kq << 3);
#pragma unroll
    for (int c = 0; c < 4; ++c) wp[c] = *(const bf16x8*)(p + (c << 5));
  }

  // cell threads: tid<256 own (unit u_l of 4, batch bq); c-state in registers
  const int u_l = tid & 3, bq = tid >> 2;
  float bias0[4], bias1[4];
  if (tid < 256) {
#pragma unroll
    for (int g = 0; g < 4; ++g) {
      bias0[g] = b0[cb + (u_l << 2) + g];
      bias1[g] = b1[cb + (u_l << 2) + g];
    }
  }
  float c0v = 0.f, c1v = 0.f;

  __shared__ float red[8][16][68];  // K-partials; 68 keeps 16B alignment

  __syncthreads();  // s_lead visible to all waves

  for (int t = 0; t < 512; ++t) {
    const __hip_bfloat16* h0prev = h0buf + ((size_t)(t & 1) << 16);
    const __hip_bfloat16* h0cur = h0buf + ((size_t)((t + 1) & 1) << 16);
    const __hip_bfloat16* h1prev = h1buf + ((size_t)((t + 2) % 3) << 16);

    // ======== phase A: gates0 = [x_t | h0prev] @ W0cat^T ========
    // h0prev L2-warm from B(t-1); x_t L2-warm from last step's prefetch.
    {
      f32x4 a0 = {0.f, 0.f, 0.f, 0.f}, a1 = a0, a2 = a0, a3 = a0;
#pragma unroll
      for (int c = 0; c < 5; ++c) {
        const int k0 = w * 160 + (c << 5);
        const __hip_bfloat16* ab;
        size_t rs;
        if (k0 < 256) {  // x part
          ab = xbf + ((size_t)t << 14) + k0 + (kq << 3);
          rs = 256;
        } else {         // h part
          ab = h0prev + (k0 - 256) + (kq << 3);
          rs = 1024;
        }
        bf16x8 f0 = *(const bf16x8*)(ab + (size_t)col * rs);
        bf16x8 f1 = *(const bf16x8*)(ab + (size_t)(16 + col) * rs);
        bf16x8 f2 = *(const bf16x8*)(ab + (size_t)(32 + col) * rs);
        bf16x8 f3 = *(const bf16x8*)(ab + (size_t)(48 + col) * rs);
        a0 = __builtin_amdgcn_mfma_f32_16x16x32_bf16(f0, wa[c], a0, 0, 0, 0);
        a1 = __builtin_amdgcn_mfma_f32_16x16x32_bf16(f1, wa[c], a1, 0, 0, 0);
        a2 = __builtin_amdgcn_mfma_f32_16x16x32_bf16(f2, wa[c], a2, 0, 0, 0);
        a3 = __builtin_amdgcn_mfma_f32_16x16x32_bf16(f3, wa[c], a3, 0, 0, 0);
      }
      *(f32x4*)&red[w][col][(kq << 2)] = a0;
      *(f32x4*)&red[w][col][16 + (kq << 2)] = a1;
      *(f32x4*)&red[w][col][32 + (kq << 2)] = a2;
      *(f32x4*)&red[w][col][48 + (kq << 2)] = a3;
    }
    __syncthreads();
    if (tid < 256) {  // 8-way K-reduce + LSTM cell 0 -> direct 2B publish
      float gg[4];
#pragma unroll
      for (int g = 0; g < 4; ++g) {
        float v = bias0[g];
#pragma unroll
        for (int ww = 0; ww < 8; ++ww) v += red[ww][(u_l << 2) + g][bq];
        gg[g] = v;
      }
      float cn = sigm(gg[1]) * c0v + sigm(gg[0]) * ftanh(gg[2]);
      c0v = cn;
      vstore_bf16((__hip_bfloat16*)h0cur + ((size_t)bq << 10) + (cb >> 2) + u_l,
                  sigm(gg[3]) * ftanh(cn));
    }
    __syncthreads();  // red free; publish stores issued

    // ---- cache hygiene in the shadow window ----
    if (w == 0) {
      __builtin_amdgcn_sched_barrier(0);
      if (s_lead) {
        // full agent acquire: waitcnt + L1/L2 inv (proven codegen, R5/R6).
        // Drain cost confined to <=16 leader blocks' wave 0.
        __builtin_amdgcn_fence(__ATOMIC_ACQUIRE, "agent");
      } else {
        asm volatile("buffer_inv" ::: "memory");  // L1-only inv, drain-free
      }
      __builtin_amdgcn_sched_barrier(0);
    }
    __syncthreads();  // inv ordered before proj / prefetch / B loads

    // ---- window work: proj out[t-2] OR x[t+1] L2-prefetch ----
    if (isproj && t >= 2) {
      // h1[t-2] lives in slot (t-2)%3 == (t+1)%3
      do_proj(h1buf + (((size_t)((t + 1) % 3)) << 16), wp, red, blin, out,
              pcol, pbat, t - 2, tid, w, col, kq);
    } else if (w < 2 && t < 511) {
      // warm L1/L2 with next step's x tile (survives: next inv is post-A(t+1))
      const char* px = (const char*)(xbf + ((size_t)(t + 1) << 14));
      const int idx = (w << 6) | lane;  // 0..127
#pragma unroll
      for (int i = 0; i < 4; ++i) {
        unsigned v = *(const unsigned*)(px + ((idx + (i << 7)) << 6));
        asm volatile("" ::"v"(v));  // keep the load
      }
    }

    // ---- drain (overlapped by the work above) + flag + poll ----
    __builtin_amdgcn_s_waitcnt(0);  // per-wave: own publishes / proj-outs
    __syncthreads();                // all waves' publishes drained
    if (tid == 0)
      __hip_atomic_store(&flags[bid], (unsigned)(t + 1), __ATOMIC_RELAXED,
                         __HIP_MEMORY_SCOPE_AGENT);
    if (w == 0) {
      const unsigned tgt = (unsigned)(t + 1);
      const u64* fq = (const u64*)flags;
      for (;;) {
        u64 q0 = __hip_atomic_load(&fq[2 * lane], __ATOMIC_RELAXED,
                                   __HIP_MEMORY_SCOPE_AGENT);
        u64 q1 = __hip_atomic_load(&fq[2 * lane + 1], __ATOMIC_RELAXED,
                                   __HIP_MEMORY_SCOPE_AGENT);
        int ok = ((unsigned)q0 >= tgt) & ((unsigned)(q0 >> 32) >= tgt) &
                 ((unsigned)q1 >= tgt) & ((unsigned)(q1 >> 32) >= tgt);
        if (__all(ok)) break;
        __builtin_amdgcn_s_sleep(1);
      }
    }
    __syncthreads();

    // ======== phase B: gates1 = [h0cur | h1prev] @ W1^T ========
    // Stale lines were dropped by this XCD's leader-inv before any flag of
    // step t was raised; misses refill from the (complete) LLC copy.
    {
      const __hip_bfloat16* ab =
          ((w < 4) ? h0cur : h1prev) + ((w & 3) << 8) + (kq << 3);
      f32x4 a0 = {0.f, 0.f, 0.f, 0.f}, a1 = a0, a2 = a0, a3 = a0;
#pragma unroll
      for (int c = 0; c < 8; ++c) {
        const __hip_bfloat16* p = ab + (c << 5);
        bf16x8 f0 = *(const bf16x8*)(p + ((size_t)col << 10));
        bf16x8 f1 = *(const bf16x8*)(p + ((size_t)(16 + col) << 10));
        bf16x8 f2 = *(const bf16x8*)(p + ((size_t)(32 + col) << 10));
        bf16x8 f3 = *(const bf16x8*)(p + ((size_t)(48 + col) << 10));
        a0 = __builtin_amdgcn_mfma_f32_16x16x32_bf16(f0, wb[c], a0, 0, 0, 0);
        a1 = __builtin_amdgcn_mfma_f32_16x16x32_bf16(f1, wb[c], a1, 0, 0, 0);
        a2 = __builtin_amdgcn_mfma_f32_16x16x32_bf16(f2, wb[c], a2, 0, 0, 0);
        a3 = __builtin_amdgcn_mfma_f32_16x16x32_bf16(f3, wb[c], a3, 0, 0, 0);
      }
      *(f32x4*)&red[w][col][(kq << 2)] = a0;
      *(f32x4*)&red[w][col][16 + (kq << 2)] = a1;
      *(f32x4*)&red[w][col][32 + (kq << 2)] = a2;
      *(f32x4*)&red[w][col][48 + (kq << 2)] = a3;
    }
    __syncthreads();
    if (tid < 256) {  // 8-way K-reduce + LSTM cell 1 -> direct 2B publish
      float gg[4];
#pragma unroll
      for (int g = 0; g < 4; ++g) {
        float v = bias1[g];
#pragma unroll
        for (int ww = 0; ww < 8; ++ww) v += red[ww][(u_l << 2) + g][bq];
        gg[g] = v;
      }
      float cn = sigm(gg[1]) * c1v + sigm(gg[0]) * ftanh(gg[2]);
      c1v = cn;
      // h1[t] -> slot t%3 (drains at next step's pre-flag waitcnt)
      vstore_bf16(h1buf + ((size_t)(t % 3) << 16) + ((size_t)bq << 10) +
                      (cb >> 2) + u_l,
                  sigm(gg[3]) * ftanh(cn));
    }
    __syncthreads();  // red safe for next iteration's phase A
  }

  // ---- tail: h1[510] in slot 0, h1[511] in slot 1 (just published) ----
  __builtin_amdgcn_s_waitcnt(0);  // per-wave drain of h1[511] publishes
  __syncthreads();
  if (tid == 0)
    __hip_atomic_store(&flags[bid], 513u, __ATOMIC_RELAXED,
                       __HIP_MEMORY_SCOPE_AGENT);
  if (!isproj) return;
  if (w == 0) {
    const u64* fq = (const u64*)flags;
    for (;;) {
      u64 q0 = __hip_atomic_load(&fq[2 * lane], __ATOMIC_RELAXED,
                                 __HIP_MEMORY_SCOPE_AGENT);
      u64 q1 = __hip_atomic_load(&fq[2 * lane + 1], __ATOMIC_RELAXED,
                                 __HIP_MEMORY_SCOPE_AGENT);
      int ok = ((unsigned)q0 >= 513u) & ((unsigned)(q0 >> 32) >= 513u) &
               ((unsigned)q1 >= 513u) & ((unsigned)(q1 >> 32) >= 513u);
      if (__all(ok)) break;
      __builtin_amdgcn_s_sleep(1);
    }
    // one-time full agent acquire: slot-1 (and slot-0) lines may be stale
    __builtin_amdgcn_fence(__ATOMIC_ACQUIRE, "agent");
  }
  __syncthreads();
  do_proj(h1buf, wp, red, blin, out, pcol, pbat, 510, tid, w, col, kq);
  __syncthreads();  // red reuse barrier between the two tail projections
  do_proj(h1buf + ((size_t)1 << 16), wp, red, blin, out, pcol, pbat, 511, tid,
          w, col, kq);
}

// ---------------- host launch ----------------

extern "C" void kernel_launch(void* const* d_in, const int* in_sizes, int n_in,
                              void* d_out, int out_size, void* d_ws, size_t ws_size,
                              hipStream_t stream) {
  const float* z = (const float*)d_in[0];
  const float* x = (const float*)d_in[1];
  const float* Wih0 = (const float*)d_in[2];
  const float* Whh0 = (const float*)d_in[3];
  const float* bih0 = (const float*)d_in[4];
  const float* bhh0 = (const float*)d_in[5];
  const float* Wih1 = (const float*)d_in[6];
  const float* Whh1 = (const float*)d_in[7];
  const float* bih1 = (const float*)d_in[8];
  const float* bhh1 = (const float*)d_in[9];
  const float* Wlin = (const float*)d_in[10];
  const float* blin = (const float*)d_in[11];
  float* out = (float*)d_out;

  char* ws = (char*)d_ws;
  __hip_bfloat16* W0 = (__hip_bfloat16*)(ws);                // 10,485,760 B
  __hip_bfloat16* W1 = (__hip_bfloat16*)(ws + 10485760);     // 17,825,792 B
  __hip_bfloat16* xbf = (__hip_bfloat16*)(ws + 28311552);    // 16,777,216 B
  float* b0 = (float*)(ws + 45088768);                       // 16,384 B
  float* b1 = (float*)(ws + 45105152);                       // 16,384 B
  __hip_bfloat16* h0buf = (__hip_bfloat16*)(ws + 45121536);  // 262,144 B (2 slots)
  __hip_bfloat16* h1buf = (__hip_bfloat16*)(ws + 45383680);  // 393,216 B (3 slots)
  unsigned* flags = (unsigned*)(ws + 45776896);              // 4,096 B (flags+lead)

  hipMemsetAsync(flags, 0, 4096, stream);  // ws is re-poisoned every call
  prep_w0<<<4096, 256, 0, stream>>>(Wih0, Whh0, W0);
  prep_w1<<<4096, 256, 0, stream>>>(Wih1, Whh1, Wlin, W1);
  prep_x<<<4096, 256, 0, stream>>>(x, xbf);
  prep_misc<<<288, 256, 0, stream>>>(bih0, bhh0, bih1, bhh1, z, b0, b1, h0buf,
                                     h1buf);

  k_persist<<<256, 512, 0, stream>>>(xbf, W0, W1, b0, b1, blin, h0buf, h1buf,
                                     out, flags);
}

// Round 5
// 8847.699 us; speedup vs baseline: 1.1618x; 1.0665x over previous
//
#include <hip/hip_runtime.h>
#include <hip/hip_bf16.h>
#include <math.h>

// LSTM decoder: B=64, T=512, IN=256, OUT=256, H=1024, 2 layers + linear head.
// Round 9: hierarchical release barrier — kill the all-poll-all LLC flag
// congestion that every prior round shared.
//  - Arrive: every block stores flags[bid]=t+1 (agent scope, as R5-R8).
//  - Only the 8 per-XCD aggregators (claim old==0) run the all-256 poll;
//    then agent-acquire fence (L1+L2 inv — aggregator IS the per-XCD
//    leader, inv count unchanged vs R6/R8); then release[xcd]=t+1.
//  - The other 248 blocks poll ONE word (their XCD's release line), then
//    L1-only buffer_inv (bid<8: full fence, XCC_ID-lies belt as in R8).
//  - All flag ops are LLC-scope -> correctness is topology-agnostic; a
//    wrong XCC_ID only changes who polls what.
//  - Kept from R8: direct 2B cell publishes, proj on blocks 64..127 in the
//    arrive->release window, x[t+1] prefetch, fast cell math, tail fix.

typedef __attribute__((ext_vector_type(8))) short bf16x8;   // 8 x bf16
typedef __attribute__((ext_vector_type(4))) float f32x4;
typedef unsigned long long u64;

__device__ __forceinline__ float sigm(float v) {
  return 1.f / (1.f + __expf(-v));
}
__device__ __forceinline__ float ftanh(float v) {
  return 2.f / (1.f + __expf(-2.f * v)) - 1.f;
}

__device__ __forceinline__ unsigned short bf16_bits(float v) {
  __hip_bfloat16 hb = __float2bfloat16(v);
  unsigned short us;
  __builtin_memcpy(&us, &hb, 2);
  return us;
}

// write-through (sc0 sc1) 2B store
__device__ __forceinline__ void vstore_bf16(__hip_bfloat16* p, float v) {
  *(volatile unsigned short*)p = bf16_bits(v);
}

// ---------------- prep kernels (one-time per launch) ----------------

// W0cat[u*4+g][k] : k<256 -> Wih0[g*1024+u][k], else Whh0[g*1024+u][k-256]
__global__ __launch_bounds__(256) void prep_w0(const float* __restrict__ Wih0,
                                               const float* __restrict__ Whh0,
                                               __hip_bfloat16* __restrict__ W0) {
  const unsigned n = 4096u * 1280u;
  for (unsigned d = blockIdx.x * blockDim.x + threadIdx.x; d < n;
       d += blockDim.x * gridDim.x) {
    unsigned r = d / 1280u;
    unsigned k = d - r * 1280u;
    unsigned u = r >> 2, g = r & 3u;
    unsigned srow = g * 1024u + u;
    float v = (k < 256u) ? Wih0[(size_t)srow * 256u + k]
                         : Whh0[(size_t)srow * 1024u + (k - 256u)];
    W0[d] = __float2bfloat16(v);
  }
}

// W1ext[4352][2048]: rows<4096 reordered LSTM1 weights [Wih1|Whh1];
// rows 4096+o: [zeros(1024) | Wlin[o]]
__global__ __launch_bounds__(256) void prep_w1(const float* __restrict__ Wih1,
                                               const float* __restrict__ Whh1,
                                               const float* __restrict__ Wlin,
                                               __hip_bfloat16* __restrict__ W1) {
  const unsigned n = 4352u * 2048u;
  for (unsigned d = blockIdx.x * blockDim.x + threadIdx.x; d < n;
       d += blockDim.x * gridDim.x) {
    unsigned r = d >> 11;
    unsigned k = d & 2047u;
    float v;
    if (r < 4096u) {
      unsigned u = r >> 2, g = r & 3u;
      unsigned srow = g * 1024u + u;
      v = (k < 1024u) ? Wih1[(size_t)srow * 1024u + k]
                      : Whh1[(size_t)srow * 1024u + (k - 1024u)];
    } else {
      unsigned o = r - 4096u;
      v = (k < 1024u) ? 0.f : Wlin[(size_t)o * 1024u + (k - 1024u)];
    }
    W1[d] = __float2bfloat16(v);
  }
}

// xbf[t][b][k] = bf16( t==0 ? 0 : x[b][t-1][k] )   (teacher forcing shift)
__global__ __launch_bounds__(256) void prep_x(const float* __restrict__ x,
                                              __hip_bfloat16* __restrict__ xbf) {
  const unsigned n = 512u * 64u * 256u;
  for (unsigned d = blockIdx.x * blockDim.x + threadIdx.x; d < n;
       d += blockDim.x * gridDim.x) {
    unsigned t = d >> 14;
    unsigned b = (d >> 8) & 63u;
    unsigned k = d & 255u;
    float v = (t == 0u) ? 0.f : x[((size_t)b * 512u + (t - 1u)) * 256u + k];
    xbf[d] = __float2bfloat16(v);
  }
}

// biases (gate-interleaved, bih+bhh combined) + h init: h0[-1] -> slot 0,
// h1[-1] -> slot 2 (h1[tau] lives in slot tau%3; tau=-1 -> 2)
__global__ __launch_bounds__(256) void prep_misc(
    const float* __restrict__ bih0, const float* __restrict__ bhh0,
    const float* __restrict__ bih1, const float* __restrict__ bhh1,
    const float* __restrict__ z, float* __restrict__ b0, float* __restrict__ b1,
    __hip_bfloat16* __restrict__ h0buf, __hip_bfloat16* __restrict__ h1buf) {
  for (int i = blockIdx.x * blockDim.x + threadIdx.x; i < 73728;
       i += blockDim.x * gridDim.x) {
    if (i < 4096) {
      int u = i >> 2, g = i & 3;
      b0[i] = bih0[g * 1024 + u] + bhh0[g * 1024 + u];
    } else if (i < 8192) {
      int r = i - 4096;
      int u = r >> 2, g = r & 3;
      b1[r] = bih1[g * 1024 + u] + bhh1[g * 1024 + u];
    } else {
      int j = i - 8192;  // 0..65535
      float zv = z[j];
      vstore_bf16(h0buf + j, zv);                       // h0 slot 0
      vstore_bf16(h1buf + 2 * 65536 + j, zv);           // h1 slot 2
    }
  }
}

// ---------------- projection helper (blocks 64..127) ----------------
// out[pbat*16 .. +16, t_out, pcol*16 .. +16) = h1p @ Wlin^T + blin

__device__ __forceinline__ void do_proj(const __hip_bfloat16* __restrict__ h1p,
                                        const bf16x8* wp, float (*red)[16][68],
                                        const float* __restrict__ blin,
                                        float* __restrict__ out, int pcol,
                                        int pbat, int t_out, int tid, int w,
                                        int col, int kq) {
  f32x4 a0 = {0.f, 0.f, 0.f, 0.f};
  const __hip_bfloat16* ab =
      h1p + ((size_t)((pbat << 4) + col) << 10) + (w << 7) + (kq << 3);
#pragma unroll
  for (int c = 0; c < 4; ++c) {
    bf16x8 f = *(const bf16x8*)(ab + (c << 5));
    a0 = __builtin_amdgcn_mfma_f32_16x16x32_bf16(f, wp[c], a0, 0, 0, 0);
  }
  *(f32x4*)&red[w][col][(kq << 2)] = a0;
  __syncthreads();
  if (tid < 256) {
    int o_l = tid & 15, b = tid >> 4;  // b: 0..15
    float v = blin[(pcol << 4) + o_l];
#pragma unroll
    for (int ww = 0; ww < 8; ++ww) v += red[ww][o_l][b];
    out[(((size_t)((pbat << 4) + b) << 9) + (size_t)t_out) * 256 + (pcol << 4) +
        o_l] = v;
  }
  // no trailing sync: every call site is followed by a block-wide barrier
  // before red is written again.
}

// ---------------- persistent kernel ----------------

__global__ __launch_bounds__(512) void k_persist(
    const __hip_bfloat16* __restrict__ xbf, const __hip_bfloat16* __restrict__ W0,
    const __hip_bfloat16* __restrict__ W1, const float* __restrict__ b0,
    const float* __restrict__ b1, const float* __restrict__ blin,
    __hip_bfloat16* __restrict__ h0buf, __hip_bfloat16* __restrict__ h1buf,
    float* __restrict__ out, unsigned* __restrict__ flags) {
  const int tid = threadIdx.x;
  const int lane = tid & 63;
  const int w = tid >> 6;          // wave id = K-split index (0..7)
  const int bid = blockIdx.x;
  const int cb = bid << 4;         // 16 gate-columns owned by this block
  const int col = lane & 15;
  const int kq = lane >> 4;
  const int n = cb + col;
  const bool isproj = (bid >= 64 && bid < 128);
  const int pcol = bid & 15;       // proj: out-col tile
  const int pbat = (bid >> 4) & 3; // proj: batch tile

  // ---- per-XCD aggregator election ----
  // flags layout (bytes): [0..1023] flags[256]; [1024..1055] lead[8];
  // [1088 + 64*x] release[x] (one line per XCD).
  __shared__ int s_agg, s_xcd;
  {
    unsigned* lead = flags + 256;
    if (tid == 0) {
      unsigned xcc = 0;
      asm volatile("s_getreg_b32 %0, hwreg(HW_REG_XCC_ID)" : "=s"(xcc));
      xcc &= 7u;
      unsigned old = __hip_atomic_fetch_add(&lead[xcc], 1u, __ATOMIC_RELAXED,
                                            __HIP_MEMORY_SCOPE_AGENT);
      s_agg = (old == 0u) ? 1 : 0;
      s_xcd = (int)xcc;
    }
  }

  // ---- weights -> registers (persist across all 512 steps) ----
  bf16x8 wa[5], wb[8], wp[4];
  {
    const __hip_bfloat16* p = W0 + (size_t)n * 1280 + w * 160 + (kq << 3);
#pragma unroll
    for (int c = 0; c < 5; ++c) wa[c] = *(const bf16x8*)(p + (c << 5));
  }
  {
    const __hip_bfloat16* p = W1 + ((size_t)n << 11) + (w << 8) + (kq << 3);
#pragma unroll
    for (int c = 0; c < 8; ++c) wb[c] = *(const bf16x8*)(p + (c << 5));
  }
  if (isproj) {
    const __hip_bfloat16* p = W1 +
        ((size_t)(4096 + (pcol << 4) + col) << 11) + 1024 + (w << 7) + (kq << 3);
#pragma unroll
    for (int c = 0; c < 4; ++c) wp[c] = *(const bf16x8*)(p + (c << 5));
  }

  // cell threads: tid<256 own (unit u_l of 4, batch bq); c-state in registers
  const int u_l = tid & 3, bq = tid >> 2;
  float bias0[4], bias1[4];
  if (tid < 256) {
#pragma unroll
    for (int g = 0; g < 4; ++g) {
      bias0[g] = b0[cb + (u_l << 2) + g];
      bias1[g] = b1[cb + (u_l << 2) + g];
    }
  }
  float c0v = 0.f, c1v = 0.f;

  __shared__ float red[8][16][68];  // K-partials; 68 keeps 16B alignment

  __syncthreads();  // s_agg/s_xcd visible to all waves

  unsigned* rel = flags + 272 + (s_xcd << 4);  // this XCD's release word

  for (int t = 0; t < 512; ++t) {
    const __hip_bfloat16* h0prev = h0buf + ((size_t)(t & 1) << 16);
    const __hip_bfloat16* h0cur = h0buf + ((size_t)((t + 1) & 1) << 16);
    const __hip_bfloat16* h1prev = h1buf + ((size_t)((t + 2) % 3) << 16);

    // ======== phase A: gates0 = [x_t | h0prev] @ W0cat^T ========
    // h0prev L2-warm from B(t-1); x_t L2-warm from last step's prefetch.
    {
      f32x4 a0 = {0.f, 0.f, 0.f, 0.f}, a1 = a0, a2 = a0, a3 = a0;
#pragma unroll
      for (int c = 0; c < 5; ++c) {
        const int k0 = w * 160 + (c << 5);
        const __hip_bfloat16* ab;
        size_t rs;
        if (k0 < 256) {  // x part
          ab = xbf + ((size_t)t << 14) + k0 + (kq << 3);
          rs = 256;
        } else {         // h part
          ab = h0prev + (k0 - 256) + (kq << 3);
          rs = 1024;
        }
        bf16x8 f0 = *(const bf16x8*)(ab + (size_t)col * rs);
        bf16x8 f1 = *(const bf16x8*)(ab + (size_t)(16 + col) * rs);
        bf16x8 f2 = *(const bf16x8*)(ab + (size_t)(32 + col) * rs);
        bf16x8 f3 = *(const bf16x8*)(ab + (size_t)(48 + col) * rs);
        a0 = __builtin_amdgcn_mfma_f32_16x16x32_bf16(f0, wa[c], a0, 0, 0, 0);
        a1 = __builtin_amdgcn_mfma_f32_16x16x32_bf16(f1, wa[c], a1, 0, 0, 0);
        a2 = __builtin_amdgcn_mfma_f32_16x16x32_bf16(f2, wa[c], a2, 0, 0, 0);
        a3 = __builtin_amdgcn_mfma_f32_16x16x32_bf16(f3, wa[c], a3, 0, 0, 0);
      }
      *(f32x4*)&red[w][col][(kq << 2)] = a0;
      *(f32x4*)&red[w][col][16 + (kq << 2)] = a1;
      *(f32x4*)&red[w][col][32 + (kq << 2)] = a2;
      *(f32x4*)&red[w][col][48 + (kq << 2)] = a3;
    }
    __syncthreads();
    if (tid < 256) {  // 8-way K-reduce + LSTM cell 0 -> direct 2B publish
      float gg[4];
#pragma unroll
      for (int g = 0; g < 4; ++g) {
        float v = bias0[g];
#pragma unroll
        for (int ww = 0; ww < 8; ++ww) v += red[ww][(u_l << 2) + g][bq];
        gg[g] = v;
      }
      float cn = sigm(gg[1]) * c0v + sigm(gg[0]) * ftanh(gg[2]);
      c0v = cn;
      vstore_bf16((__hip_bfloat16*)h0cur + ((size_t)bq << 10) + (cb >> 2) + u_l,
                  sigm(gg[3]) * ftanh(cn));
    }
    __syncthreads();  // red free; publish stores issued

    // ---- window work: proj out[t-2] OR x[t+1] L2-prefetch ----
    // Proj reads h1[t-2] (slot (t+1)%3): every cached copy of that slot
    // postdates the fence at barrier(t-1), which postdates the h1[t-2]
    // drain -> data is fresh without a fence here.
    if (isproj && t >= 2) {
      do_proj(h1buf + (((size_t)((t + 1) % 3)) << 16), wp, red, blin, out,
              pcol, pbat, t - 2, tid, w, col, kq);
    } else if (w < 2 && t < 511) {
      const char* px = (const char*)(xbf + ((size_t)(t + 1) << 14));
      const int idx = (w << 6) | lane;  // 0..127
#pragma unroll
      for (int i = 0; i < 4; ++i) {
        unsigned v = *(const unsigned*)(px + ((idx + (i << 7)) << 6));
        asm volatile("" ::"v"(v));  // keep the load
      }
    }

    // ---- drain + arrive + hierarchical release ----
    __builtin_amdgcn_s_waitcnt(0);  // per-wave: publishes / proj-outs drained
    __syncthreads();                // all waves drained before the flag
    if (tid == 0)
      __hip_atomic_store(&flags[bid], (unsigned)(t + 1), __ATOMIC_RELAXED,
                         __HIP_MEMORY_SCOPE_AGENT);
    if (w == 0) {
      const unsigned tgt = (unsigned)(t + 1);
      if (s_agg) {
        // aggregator: the ONLY all-256 poller on this XCD
        const u64* fq = (const u64*)flags;
        for (;;) {
          u64 q0 = __hip_atomic_load(&fq[2 * lane], __ATOMIC_RELAXED,
                                     __HIP_MEMORY_SCOPE_AGENT);
          u64 q1 = __hip_atomic_load(&fq[2 * lane + 1], __ATOMIC_RELAXED,
                                     __HIP_MEMORY_SCOPE_AGENT);
          int ok = ((unsigned)q0 >= tgt) & ((unsigned)(q0 >> 32) >= tgt) &
                   ((unsigned)q1 >= tgt) & ((unsigned)(q1 >> 32) >= tgt);
          if (__all(ok)) break;
          __builtin_amdgcn_s_sleep(1);
        }
        // per-XCD leader fence: waitcnt + L1/L2 inv (proven codegen)
        __builtin_amdgcn_fence(__ATOMIC_ACQUIRE, "agent");
        if (lane == 0)
          __hip_atomic_store(rel, tgt, __ATOMIC_RELAXED,
                             __HIP_MEMORY_SCOPE_AGENT);
      } else {
        // 248 blocks poll ONE word: their XCD's release line
        while (__hip_atomic_load(rel, __ATOMIC_RELAXED,
                                 __HIP_MEMORY_SCOPE_AGENT) < tgt)
          __builtin_amdgcn_s_sleep(1);
        if (bid < 8) {
          // belt: full fence in case XCC_ID lies about topology
          __builtin_amdgcn_fence(__ATOMIC_ACQUIRE, "agent");
        } else {
          __builtin_amdgcn_sched_barrier(0);
          asm volatile("buffer_inv" ::: "memory");  // L1-only inv
          __builtin_amdgcn_sched_barrier(0);
        }
      }
    }
    __syncthreads();

    // ======== phase B: gates1 = [h0cur | h1prev] @ W1^T ========
    // Stale L2 lines were dropped by this XCD's aggregator fence before
    // release; misses refill from the (complete) LLC copy.
    {
      const __hip_bfloat16* ab =
          ((w < 4) ? h0cur : h1prev) + ((w & 3) << 8) + (kq << 3);
      f32x4 a0 = {0.f, 0.f, 0.f, 0.f}, a1 = a0, a2 = a0, a3 = a0;
#pragma unroll
      for (int c = 0; c < 8; ++c) {
        const __hip_bfloat16* p = ab + (c << 5);
        bf16x8 f0 = *(const bf16x8*)(p + ((size_t)col << 10));
        bf16x8 f1 = *(const bf16x8*)(p + ((size_t)(16 + col) << 10));
        bf16x8 f2 = *(const bf16x8*)(p + ((size_t)(32 + col) << 10));
        bf16x8 f3 = *(const bf16x8*)(p + ((size_t)(48 + col) << 10));
        a0 = __builtin_amdgcn_mfma_f32_16x16x32_bf16(f0, wb[c], a0, 0, 0, 0);
        a1 = __builtin_amdgcn_mfma_f32_16x16x32_bf16(f1, wb[c], a1, 0, 0, 0);
        a2 = __builtin_amdgcn_mfma_f32_16x16x32_bf16(f2, wb[c], a2, 0, 0, 0);
        a3 = __builtin_amdgcn_mfma_f32_16x16x32_bf16(f3, wb[c], a3, 0, 0, 0);
      }
      *(f32x4*)&red[w][col][(kq << 2)] = a0;
      *(f32x4*)&red[w][col][16 + (kq << 2)] = a1;
      *(f32x4*)&red[w][col][32 + (kq << 2)] = a2;
      *(f32x4*)&red[w][col][48 + (kq << 2)] = a3;
    }
    __syncthreads();
    if (tid < 256) {  // 8-way K-reduce + LSTM cell 1 -> direct 2B publish
      float gg[4];
#pragma unroll
      for (int g = 0; g < 4; ++g) {
        float v = bias1[g];
#pragma unroll
        for (int ww = 0; ww < 8; ++ww) v += red[ww][(u_l << 2) + g][bq];
        gg[g] = v;
      }
      float cn = sigm(gg[1]) * c1v + sigm(gg[0]) * ftanh(gg[2]);
      c1v = cn;
      // h1[t] -> slot t%3 (drains at next step's pre-flag waitcnt)
      vstore_bf16(h1buf + ((size_t)(t % 3) << 16) + ((size_t)bq << 10) +
                      (cb >> 2) + u_l,
                  sigm(gg[3]) * ftanh(cn));
    }
    __syncthreads();  // red safe for next iteration's phase A
  }

  // ---- tail: h1[510] in slot 0, h1[511] in slot 1 (just published) ----
  __builtin_amdgcn_s_waitcnt(0);  // per-wave drain of h1[511] publishes
  __syncthreads();
  if (tid == 0)
    __hip_atomic_store(&flags[bid], 513u, __ATOMIC_RELAXED,
                       __HIP_MEMORY_SCOPE_AGENT);
  if (w == 0 && s_agg) {
    const u64* fq = (const u64*)flags;
    for (;;) {
      u64 q0 = __hip_atomic_load(&fq[2 * lane], __ATOMIC_RELAXED,
                                 __HIP_MEMORY_SCOPE_AGENT);
      u64 q1 = __hip_atomic_load(&fq[2 * lane + 1], __ATOMIC_RELAXED,
                                 __HIP_MEMORY_SCOPE_AGENT);
      int ok = ((unsigned)q0 >= 513u) & ((unsigned)(q0 >> 32) >= 513u) &
               ((unsigned)q1 >= 513u) & ((unsigned)(q1 >> 32) >= 513u);
      if (__all(ok)) break;
      __builtin_amdgcn_s_sleep(1);
    }
    __builtin_amdgcn_fence(__ATOMIC_ACQUIRE, "agent");
    if (lane == 0)
      __hip_atomic_store(rel, 513u, __ATOMIC_RELAXED,
                         __HIP_MEMORY_SCOPE_AGENT);
  }
  if (!isproj) return;
  if (w == 0 && !s_agg) {
    while (__hip_atomic_load(rel, __ATOMIC_RELAXED,
                             __HIP_MEMORY_SCOPE_AGENT) < 513u)
      __builtin_amdgcn_s_sleep(1);
    // one-time full acquire before reading h1[510]/h1[511]
    __builtin_amdgcn_fence(__ATOMIC_ACQUIRE, "agent");
  }
  __syncthreads();
  do_proj(h1buf, wp, red, blin, out, pcol, pbat, 510, tid, w, col, kq);
  __syncthreads();  // red reuse barrier between the two tail projections
  do_proj(h1buf + ((size_t)1 << 16), wp, red, blin, out, pcol, pbat, 511, tid,
          w, col, kq);
}

// ---------------- host launch ----------------

extern "C" void kernel_launch(void* const* d_in, const int* in_sizes, int n_in,
                              void* d_out, int out_size, void* d_ws, size_t ws_size,
                              hipStream_t stream) {
  const float* z = (const float*)d_in[0];
  const float* x = (const float*)d_in[1];
  const float* Wih0 = (const float*)d_in[2];
  const float* Whh0 = (const float*)d_in[3];
  const float* bih0 = (const float*)d_in[4];
  const float* bhh0 = (const float*)d_in[5];
  const float* Wih1 = (const float*)d_in[6];
  const float* Whh1 = (const float*)d_in[7];
  const float* bih1 = (const float*)d_in[8];
  const float* bhh1 = (const float*)d_in[9];
  const float* Wlin = (const float*)d_in[10];
  const float* blin = (const float*)d_in[11];
  float* out = (float*)d_out;

  char* ws = (char*)d_ws;
  __hip_bfloat16* W0 = (__hip_bfloat16*)(ws);                // 10,485,760 B
  __hip_bfloat16* W1 = (__hip_bfloat16*)(ws + 10485760);     // 17,825,792 B
  __hip_bfloat16* xbf = (__hip_bfloat16*)(ws + 28311552);    // 16,777,216 B
  float* b0 = (float*)(ws + 45088768);                       // 16,384 B
  float* b1 = (float*)(ws + 45105152);                       // 16,384 B
  __hip_bfloat16* h0buf = (__hip_bfloat16*)(ws + 45121536);  // 262,144 B (2 slots)
  __hip_bfloat16* h1buf = (__hip_bfloat16*)(ws + 45383680);  // 393,216 B (3 slots)
  unsigned* flags = (unsigned*)(ws + 45776896);              // 4,096 B

  hipMemsetAsync(flags, 0, 4096, stream);  // ws is re-poisoned every call
  prep_w0<<<4096, 256, 0, stream>>>(Wih0, Whh0, W0);
  prep_w1<<<4096, 256, 0, stream>>>(Wih1, Whh1, Wlin, W1);
  prep_x<<<4096, 256, 0, stream>>>(x, xbf);
  prep_misc<<<288, 256, 0, stream>>>(bih0, bhh0, bih1, bhh1, z, b0, b1, h0buf,
                                     h1buf);

  k_persist<<<256, 512, 0, stream>>>(xbf, W0, W1, b0, b1, blin, h0buf, h1buf,
                                     out, flags);
}